// Round 2
// baseline (240.235 us; speedup 1.0000x reference)
//
#include <hip/hip_runtime.h>

#define RAD 6
#define KS 13
#define DIM 192
#define CH 3
#define W4C 48                 // float4 per row
#define PLANE4 (DIM * W4C)     // f4 per (d) plane = 9216
#define VOL4 (DIM * PLANE4)    // f4 per channel
#define VOL (DIM * DIM * DIM)
#define TOTAL (CH * VOL)       // 21,233,664 floats

// ---------------- fused kernel geometry ----------------
#define HT 8                   // output h-rows per block
#define HL 20                  // staged rows = HT + 2*RAD
#define DT 12                  // output depths per block
#define NDT 16                 // 16*12 = 192 exact
#define NSTEP (DT + 2 * RAD)   // 24 planes streamed per block
#define NTF 192
#define NHT (DIM / HT)         // 24 h-tiles
#define GRIDF (CH * NHT * NDT) // 1152 blocks = 8 XCD * 144
#define RS 49                  // raw LDS row stride in f4 (48 + 1 pad: 2-way max)
#define WCS 49                 // w-conv LDS row stride in f4

typedef float nt4 __attribute__((ext_vector_type(4)));  // for nontemporal stores

// Extract 1D gaussian: g3[i][j][k] = g1[i]*g1[j]*g1[k], sum(g1)=1 -> row-sum recovers g1.
__global__ void g1_extract_kernel(const float* __restrict__ w, float* __restrict__ g1) {
    int i = threadIdx.x;
    if (i < KS) {
        float s = 0.f;
        for (int j = 0; j < KS * KS; ++j) s += w[i * KS * KS + j];
        g1[i] = s;
    }
}

// ---------------------------------------------------------------------------
// Single-pass separable conv: block = (c, 8 h-rows x full w, 12 depths).
// Streams NSTEP=24 input planes along d. Per plane:
//   stage: 20 rows x 48 f4 -> raw LDS (5 coalesced f4/thread, rows pj+4i)
//   W:     160 run-threads, each 6 f4 outputs from a 10-f4 register window
//          (w zero-pad via 4 selects; h zero-pad via rowScale on output)
//   H:     192 threads, each a (w4, 2-row) column pair: 14 ds_read_b128
//          shared across both rows -> two WH values
//   D:     per-column 14-deep register window, pair-stepped (dot at offset
//          0/1, shift-by-2 once per pair); store when window spans o+-6.
// 2 barriers/step. LDS 31.4 KB -> 5 blocks/CU cap; grid 4.5 blocks/CU.
// ---------------------------------------------------------------------------
__global__ __launch_bounds__(NTF) void conv3d_fused(const float* __restrict__ in,
                                                    float* __restrict__ out,
                                                    const float* __restrict__ g1v) {
    __shared__ float4 raw[HL * RS];
    __shared__ float4 wcb[HL * WCS];

    int bid = blockIdx.x;
    // bijective XCD swizzle: 1152 = 8 * 144 -> each XCD gets contiguous logical range
    bid = (bid & 7) * (GRIDF / 8) + (bid >> 3);
    const int ht = bid % NHT;
    const int dt = (bid / NHT) % NDT;
    const int c  = bid / (NHT * NDT);
    const int h0 = ht * HT;
    const int d0 = dt * DT;
    const int t  = threadIdx.x;

    float g[KS];
#pragma unroll
    for (int k = 0; k < KS; ++k) g[k] = g1v[k];

    const float4* __restrict__ in4 = (const float4*)in;
    float4* __restrict__ out4 = (float4*)out;
    const float4 z4 = make_float4(0.f, 0.f, 0.f, 0.f);

    // ---- roles ----
    const int w4 = t % W4C;          // 0..47
    const int pj = t / W4C;          // 0..3

    // staging: thread stages rows (pj + 4i), col w4  (5 * 192 = 960 = 20*48 exact)
    int srcOff[5];
#pragma unroll
    for (int i = 0; i < 5; ++i) {
        int r = pj + 4 * i;
        int h = h0 - RAD + r;
        int hc = min(max(h, 0), DIM - 1);
        srcOff[i] = c * VOL4 + hc * W4C + w4;     // + dp*PLANE4 per step
    }

    // W-run role (t < 160): row u = t>>3, segment seg = t&7 (6 f4 outputs each)
    const int u_run = t >> 3;
    const int seg = t & 7;
    const bool runActive = (t < HL * 8);
    const int hrow = h0 - RAD + u_run;
    const float rowScale = (hrow >= 0 && hrow < DIM) ? 1.f : 0.f;  // h zero-pad
    const bool segLo = (seg == 0);
    const bool segHi = (seg == 7);
    const int rawRow = u_run * RS;
    const int wcBase = u_run * WCS + seg * 6;

    // H/D role: column w4, output rows h0+2pj, h0+2pj+1
    const int tapBase = 2 * pj * WCS + w4;
    const int outBase = c * VOL4 + (h0 + 2 * pj) * W4C + w4;  // + o*PLANE4

    float4 WA[14], WB[14];
#pragma unroll
    for (int j = 0; j < 14; ++j) { WA[j] = z4; WB[j] = z4; }

#pragma unroll 1
    for (int s2 = 0; s2 < NSTEP; s2 += 2) {
#pragma unroll
        for (int off = 0; off < 2; ++off) {
            const int s = s2 + off;
            const int dp = d0 - RAD + s;               // input plane
            const bool dpv = (dp >= 0) && (dp < DIM);  // block-uniform
            float4 whA = z4, whB = z4;
            if (dpv) {
                const int pb = dp * PLANE4;
                // ---- stage plane slab -> raw LDS ----
#pragma unroll
                for (int i = 0; i < 5; ++i) {
                    float4 v = in4[pb + srcOff[i]];
                    raw[(pj + 4 * i) * RS + w4] = v;
                }
                __syncthreads();
                // ---- W conv: runs of 6 f4 ----
                if (runActive) {
                    float F[40];
#pragma unroll
                    for (int i = 0; i < 10; ++i) {
                        int cw = seg * 6 - 2 + i;
                        int cwc = min(max(cw, 0), W4C - 1);
                        float4 v = raw[rawRow + cwc];
                        if ((segLo && i < 2) || (segHi && i >= 8)) v = z4;  // w zero-pad
                        F[4*i+0] = v.x; F[4*i+1] = v.y;
                        F[4*i+2] = v.z; F[4*i+3] = v.w;
                    }
#pragma unroll
                    for (int q = 0; q < 6; ++q) {
                        float ax = 0.f, ay = 0.f, az = 0.f, aw = 0.f;
#pragma unroll
                        for (int k = 0; k < KS; ++k) {
                            const float gw = g[k];
                            ax += gw * F[4*q + 2 + k];
                            ay += gw * F[4*q + 3 + k];
                            az += gw * F[4*q + 4 + k];
                            aw += gw * F[4*q + 5 + k];
                        }
                        wcb[wcBase + q] = make_float4(ax * rowScale, ay * rowScale,
                                                      az * rowScale, aw * rowScale);
                    }
                }
                __syncthreads();
                // ---- H conv: 14 taps shared by the 2-row pair ----
                float4 T[14];
#pragma unroll
                for (int k = 0; k < 14; ++k) T[k] = wcb[tapBase + k * WCS];
#pragma unroll
                for (int k = 0; k < KS; ++k) {
                    const float gw = g[k];
                    whA.x += gw * T[k].x;   whA.y += gw * T[k].y;
                    whA.z += gw * T[k].z;   whA.w += gw * T[k].w;
                    whB.x += gw * T[k+1].x; whB.y += gw * T[k+1].y;
                    whB.z += gw * T[k+1].z; whB.w += gw * T[k+1].w;
                }
            }
            // ---- D window insert + dot ----
            if (off == 0) { WA[12] = whA; WB[12] = whB; }
            else          { WA[13] = whA; WB[13] = whB; }
            if (s2 >= 2 * RAD) {
                const int o = d0 + s - 2 * RAD;        // always < DIM (exact tiling)
                float4 A = z4, B = z4;
#pragma unroll
                for (int j = 0; j < KS; ++j) {
                    const float gw = g[j];
                    const float4 a = WA[j + off];
                    const float4 b = WB[j + off];
                    A.x += gw * a.x; A.y += gw * a.y; A.z += gw * a.z; A.w += gw * a.w;
                    B.x += gw * b.x; B.y += gw * b.y; B.z += gw * b.z; B.w += gw * b.w;
                }
                const int ob = outBase + o * PLANE4;
                __builtin_nontemporal_store(*(const nt4*)&A, (nt4*)&out4[ob]);
                __builtin_nontemporal_store(*(const nt4*)&B, (nt4*)&out4[ob + W4C]);
            }
        }
        // shift window by 2 (once per pair)
#pragma unroll
        for (int j = 0; j < 12; ++j) { WA[j] = WA[j + 2]; WB[j] = WB[j + 2]; }
    }
}

// Fallback: direct 2197-tap depthwise conv (only if ws_size is too small).
__global__ void naive_conv3d_kernel(const float* __restrict__ x, const float* __restrict__ w,
                                    float* __restrict__ out, int total) {
    int n = blockIdx.x * blockDim.x + threadIdx.x;
    if (n >= total) return;
    int wp = n % DIM;
    int h = (n / DIM) % DIM;
    int d = (n / (DIM * DIM)) % DIM;
    int c = n / (DIM * DIM * DIM);
    const float* wc = w + c * KS * KS * KS;
    const float* xc = x + (size_t)c * DIM * DIM * DIM;
    float acc = 0.f;
    for (int kd = 0; kd < KS; ++kd) {
        int dd = d + kd - RAD;
        if (dd < 0 || dd >= DIM) continue;
        for (int kh = 0; kh < KS; ++kh) {
            int hh = h + kh - RAD;
            if (hh < 0 || hh >= DIM) continue;
            for (int kw = 0; kw < KS; ++kw) {
                int ww = wp + kw - RAD;
                if (ww < 0 || ww >= DIM) continue;
                acc += wc[(kd * KS + kh) * KS + kw] * xc[((size_t)dd * DIM + hh) * DIM + ww];
            }
        }
    }
    out[n] = acc;
}

extern "C" void kernel_launch(void* const* d_in, const int* in_sizes, int n_in,
                              void* d_out, int out_size, void* d_ws, size_t ws_size,
                              hipStream_t stream) {
    const float* x = (const float*)d_in[0];
    const float* w = (const float*)d_in[1];
    float* out = (float*)d_out;

    if (ws_size >= 64) {
        float* g1 = (float*)d_ws;
        g1_extract_kernel<<<1, 64, 0, stream>>>(w, g1);
        conv3d_fused<<<GRIDF, NTF, 0, stream>>>(x, out, g1);
    } else {
        const int threads = 256;
        const int blocks = (TOTAL + threads - 1) / threads;
        naive_conv3d_kernel<<<blocks, threads, 0, stream>>>(x, w, out, TOTAL);
    }
}